// Round 16
// baseline (157.787 us; speedup 1.0000x reference)
//
#include <hip/hip_runtime.h>
#include <hip/hip_bf16.h>
#include <stdint.h>

#define C_IN 512
#define HW 4096
#define NPIX 65536
#define KPAD 544
#define KIN 537
#define HID 512

typedef __attribute__((ext_vector_type(8))) short bf16x8;
typedef __attribute__((ext_vector_type(4))) float f32x4;

// native cast (RTNE; compiler lowers to v_cvt_*bf16 per m240)
__device__ __forceinline__ unsigned short f2bf(float f) {
  union { __hip_bfloat16 h; unsigned short u; } v;
  v.h = __float2bfloat16(f);
  return v.u;
}
__device__ __forceinline__ float bf2f(unsigned short h) {
  union { uint32_t u; float f; } v; v.u = ((uint32_t)h) << 16;
  return v.f;
}

// ---------- W: fp32 (512x537) -> bf16 (512x544, zero-padded cols) ----------
__global__ void k_wconv(const float* __restrict__ W, unsigned short* __restrict__ Wb) {
  int idx = blockIdx.x * 256 + threadIdx.x;
  if (idx >= HID * KPAD) return;
  int o = idx / KPAD;
  int k = idx - o * KPAD;
  float v = (k < KIN) ? W[o * KIN + k] : 0.f;
  Wb[idx] = f2bf(v);
}

// ---------- x fp32 [c][n] -> featB bf16 [n][c] (convert once, coalesced) ----------
__global__ __launch_bounds__(256, 8) void k_xpose(const float* __restrict__ x,
                                                  unsigned short* __restrict__ featB) {
  __shared__ unsigned short sm[64][70];
  int g = blockIdx.x;
  int b = g >> 9, cg = (g >> 6) & 7, pt = g & 63;
  int c0 = cg * 64, p0 = pt * 64;
  int t = threadIdx.x, lane = t & 63, w = t >> 6;
  const float* xb = x + ((size_t)b * C_IN + c0) * HW + p0;
#pragma unroll
  for (int i = 0; i < 8; ++i) {
    int ch = w * 16 + i * 2;
    float a = xb[(size_t)ch * HW + lane];
    float bq = xb[(size_t)(ch + 1) * HW + lane];
    uint32_t pk = (uint32_t)f2bf(a) | ((uint32_t)f2bf(bq) << 16);
    *(uint32_t*)&sm[lane][ch] = pk;   // ch even, 4B-aligned
  }
  __syncthreads();
#pragma unroll
  for (int i = 0; i < 2; ++i) {
    int px = (t >> 3) + i * 32, kg = t & 7;
    int n = b * 4096 + p0 + px;
    *(bf16x8*)(featB + (size_t)n * KPAD + c0 + kg * 8) = *(const bf16x8*)&sm[px][kg * 8];
  }
}

// ---------- MFMA correlation: band-harvest, part dj-stride-8 ----------
// Round-16 change vs round 15 (isolated pair): part re-laid-out as
//   part[((cs*5+di)*NPIX + n)*8 + dj']   (dj' innermost, PADDED to 8)
// -> k_norm reads one aligned b128 per (cs,di) (was ~5 scalar u16 loads);
// k_corr store offset = 8r+djp = 28tq + 7qq + 4bi + i15: contiguous within
// each 16-lane group (4x32B segments/store, was 1x128B - minor cost).
// Also: manual 5-op RTNE f2bf replaced by native __float2bfloat16 (same RTNE).
#define PADC 72
__device__ __forceinline__ int xelem(int sr, int sc, int kg) {
  return (sr * 20 + sc) * PADC + kg * 8;
}

__global__ __launch_bounds__(256, 8) void k_corr(const unsigned short* __restrict__ featB,
                                                 unsigned short* __restrict__ part) {
  __shared__ unsigned short xt[8 * 20 * PADC];  // 23,040 B
  int g = blockIdx.x;
  int bid = (g & 7) * 1024 + (g >> 3);  // bijective XCD swizzle (grid = 8*1024)
  int cs = bid & 7;
  int cg = (bid >> 3) & 3;
  int rg = (bid >> 5) & 15;
  int b  = bid >> 9;
  int t = threadIdx.x;
  int lane = t & 63;
  int w = t >> 6;
  int r0 = rg * 4, c0 = cg * 16;

  // ---- stage: 1280 = 5*256 (px,kg) items from featB; 8 lanes = one px's 128B
  bf16x8 v[5];
  int la[5];
#pragma unroll
  for (int i = 0; i < 5; ++i) {
    int flat = t + i * 256;
    int kg = flat & 7, pxi = flat >> 3;
    int sc = pxi % 20, sr = pxi / 20;
    int ir = r0 - 2 + sr, ic = c0 - 2 + sc;
    la[i] = xelem(sr, sc, kg);
    if ((unsigned)ir < 64u && (unsigned)ic < 64u) {
      int n = b * 4096 + ir * 64 + ic;
      v[i] = *(const bf16x8*)(featB + (size_t)n * KPAD + cs * 64 + kg * 8);
    } else {
      v[i] = (bf16x8){0, 0, 0, 0, 0, 0, 0, 0};
    }
  }
#pragma unroll
  for (int i = 0; i < 5; ++i)
    *(bf16x8*)&xt[la[i]] = v[i];
  __syncthreads();

  int i15 = lane & 15;
  int tq = lane >> 4;

  bf16x8 afr[2];                        // A-frags: centers, reused for all 25
#pragma unroll
  for (int ks = 0; ks < 2; ++ks)
    afr[ks] = *(const bf16x8*)&xt[xelem(w + 2, 2 + i15, ks * 4 + tq)];

  // band geometry (di-independent): reg q of beta-tile bi holds pixel r=4tq+q
  // at dj' = 4bi + i15 - r; served half: bi=0 -> r<=7, bi=1 -> r>=8.
  int nb = b * 4096 + (r0 + w) * 64 + c0;
  int addr28 = 28 * tq + i15;           // per-lane part of 8r+djp
  bool take[2][4];
#pragma unroll
  for (int bi = 0; bi < 2; ++bi)
#pragma unroll
    for (int qq = 0; qq < 4; ++qq) {
      int r = 4 * tq + qq;
      int djp = bi * 4 + i15 - r;
      take[bi][qq] = (djp >= 0) && (djp <= 4) && (bi == 0 ? (r <= 7) : (r >= 8));
    }

#pragma unroll 1
  for (int di = 0; di < 5; ++di) {
    int sr = w + di;
    unsigned short* pb = part + ((size_t)(cs * 5 + di) * NPIX + nb) * 8;
#pragma unroll
    for (int bi = 0; bi < 2; ++bi) {
      f32x4 acc = (f32x4){0.f, 0.f, 0.f, 0.f};
#pragma unroll
      for (int ks = 0; ks < 2; ++ks) {
        bf16x8 bfr = *(const bf16x8*)&xt[xelem(sr, bi * 4 + i15, ks * 4 + tq)];
        acc = __builtin_amdgcn_mfma_f32_16x16x32_bf16(afr[ks], bfr, acc, 0, 0, 0);
      }
#pragma unroll
      for (int qq = 0; qq < 4; ++qq)
        if (take[bi][qq])
          pb[addr28 + 7 * qq + 4 * bi] = f2bf(acc[qq]);
    }
  }
}

// ---------- reduce 8 partials, L2-normalize, emit featB[n][512..543] ----------
__global__ void k_norm(const unsigned short* __restrict__ part,
                       unsigned short* __restrict__ featB) {
  int n = blockIdx.x * 256 + threadIdx.x;
  float g[25];
#pragma unroll
  for (int k = 0; k < 25; ++k) g[k] = 0.f;
#pragma unroll
  for (int di = 0; di < 5; ++di)
#pragma unroll
    for (int cs = 0; cs < 8; ++cs) {
      bf16x8 vv = *(const bf16x8*)(part + ((size_t)(cs * 5 + di) * NPIX + n) * 8);
#pragma unroll
      for (int dj = 0; dj < 5; ++dj)
        g[di * 5 + dj] += bf2f((unsigned short)vv[dj]);
    }
  float ss = 0.f;
#pragma unroll
  for (int k = 0; k < 25; ++k) ss += g[k] * g[k];
  float inv = 1.0f / sqrtf(ss + 1e-6f);
  unsigned short buf[32];
#pragma unroll
  for (int k = 0; k < 25; ++k) buf[k] = f2bf(g[k] * inv);
#pragma unroll
  for (int k = 25; k < 32; ++k) buf[k] = 0;
#pragma unroll
  for (int j = 0; j < 4; ++j)
    *(bf16x8*)(featB + (size_t)n * KPAD + 512 + j * 8) = *(bf16x8*)&buf[j * 8];
}

// ---------- GEMM: out(512 x 65536) = Wb(512 x 544) * featB(65536 x 544)^T ----------
typedef __attribute__((address_space(3))) unsigned int as3_uint;
typedef const __attribute__((address_space(1))) unsigned int as1_uint;

__device__ __forceinline__ void glds16(const void* g, void* l) {
  __builtin_amdgcn_global_load_lds((as1_uint*)g, (as3_uint*)l, 16, 0, 0);
}

__global__ __launch_bounds__(256) void k_gemm(const unsigned short* __restrict__ Wb,
                                              const unsigned short* __restrict__ featB,
                                              const float* __restrict__ bias,
                                              float* __restrict__ out) {
  __shared__ __attribute__((aligned(16))) unsigned short As[2][4096]; // [128 m][32 k], swz
  __shared__ __attribute__((aligned(16))) unsigned short Bs[2][4096]; // [128 n][32 k], swz
  int g = blockIdx.x;
  int bid = (g & 7) * 256 + (g >> 3);
  int mt = bid & 3;
  int nt = bid >> 2;
  int m0 = mt * 128;
  int n0 = nt * 128;
  int tid = threadIdx.x;
  int wave = tid >> 6;
  int lane = tid & 63;
  int wm = wave >> 1;
  int wn = wave & 1;
  int kg = lane >> 4;

  uint32_t aOff[4], bOff[4];
#pragma unroll
  for (int r = 0; r < 4; ++r) {
    int rr = wm * 64 + r * 16 + (lane & 15);
    aOff[r] = rr * 64 + ((kg ^ ((rr >> 1) & 3)) << 4);
  }
#pragma unroll
  for (int cb = 0; cb < 4; ++cb) {
    int rr = wn * 64 + cb * 16 + (lane & 15);
    bOff[cb] = rr * 64 + ((kg ^ ((rr >> 1) & 3)) << 4);
  }

  f32x4 acc[4][4];
#pragma unroll
  for (int r = 0; r < 4; ++r)
#pragma unroll
    for (int cb = 0; cb < 4; ++cb)
      acc[r][cb] = (f32x4){0.f, 0.f, 0.f, 0.f};

  auto STAGE = [&](int buf, int k0) {
#pragma unroll
    for (int qq = 0; qq < 2; ++qq) {
      int ci = wave * 2 + qq;
      int i = ci * 64 + lane;
      int rr = i >> 2;
      int slot = i & 3;
      int k8 = slot ^ ((rr >> 1) & 3);
      glds16(Wb + (size_t)(m0 + rr) * KPAD + k0 + k8 * 8, (char*)&As[buf][0] + ci * 1024);
      glds16(featB + (size_t)(n0 + rr) * KPAD + k0 + k8 * 8, (char*)&Bs[buf][0] + ci * 1024);
    }
  };

  STAGE(0, 0);
  __syncthreads();
  int cur = 0;
#pragma unroll 1
  for (int t = 0; t < 17; ++t) {
    if (t < 16) STAGE(cur ^ 1, (t + 1) * 32);
    const char* Ab = (const char*)&As[cur][0];
    const char* Bb = (const char*)&Bs[cur][0];
    bf16x8 af[4], bf[4];
#pragma unroll
    for (int r = 0; r < 4; ++r)
      af[r] = *(const bf16x8*)(Ab + aOff[r]);
#pragma unroll
    for (int cb = 0; cb < 4; ++cb)
      bf[cb] = *(const bf16x8*)(Bb + bOff[cb]);
#pragma unroll
    for (int cb = 0; cb < 4; ++cb)
#pragma unroll
      for (int r = 0; r < 4; ++r)
        acc[r][cb] = __builtin_amdgcn_mfma_f32_16x16x32_bf16(af[r], bf[cb], acc[r][cb], 0, 0, 0);
    __syncthreads();
    cur ^= 1;
  }

  int bb = n0 >> 12;
  int hwb = n0 & 4095;
  float* outb = out + (size_t)bb * (HID * HW) + hwb;
#pragma unroll
  for (int r = 0; r < 4; ++r) {
    int row0 = m0 + wm * 64 + r * 16 + (lane >> 4) * 4;
    float bv[4];
#pragma unroll
    for (int j = 0; j < 4; ++j) bv[j] = bias[row0 + j];
#pragma unroll
    for (int cb = 0; cb < 4; ++cb) {
      int col = wn * 64 + cb * 16 + (lane & 15);
#pragma unroll
      for (int j = 0; j < 4; ++j) {
        float v2 = acc[r][cb][j] + bv[j];
        v2 = fmaxf(v2, 0.f);
        outb[(size_t)(row0 + j) * HW + col] = v2;
      }
    }
  }
}

extern "C" void kernel_launch(void* const* d_in, const int* in_sizes, int n_in,
                              void* d_out, int out_size, void* d_ws, size_t ws_size,
                              hipStream_t stream) {
  const float* x = (const float*)d_in[0];
  const float* W = (const float*)d_in[1];
  const float* bias = (const float*)d_in[2];
  float* out = (float*)d_out;
  char* ws = (char*)d_ws;
  // ws: featB 65536x544 bf16 = 71,303,168; Wb 512x544 bf16 = 557,056;
  //     part 40 x 65536 x 8 bf16 = 41,943,040  (total ~113.8 MB)
  unsigned short* featB = (unsigned short*)ws;
  unsigned short* Wb = (unsigned short*)(ws + 71303168);
  unsigned short* part = (unsigned short*)(ws + 71860224);

  k_wconv<<<1088, 256, 0, stream>>>(W, Wb);
  k_xpose<<<8192, 256, 0, stream>>>(x, featB);
  k_corr<<<8192, 256, 0, stream>>>(featB, part);
  k_norm<<<256, 256, 0, stream>>>(part, featB);
  k_gemm<<<2048, 256, 0, stream>>>(Wb, featB, bias, out);
}

// Round 17
// 146.914 us; speedup vs baseline: 1.0740x; 1.0740x over previous
//
#include <hip/hip_runtime.h>
#include <stdint.h>

#define C_IN 512
#define HW 4096
#define NPIX 65536
#define KPAD 544
#define KIN 537
#define HID 512

typedef __attribute__((ext_vector_type(8))) short bf16x8;
typedef __attribute__((ext_vector_type(4))) float f32x4;

__device__ __forceinline__ unsigned short f2bf(float f) {
  union { float f; uint32_t u; } v; v.f = f;
  uint32_t u = v.u;
  return (unsigned short)((u + 0x7fffu + ((u >> 16) & 1u)) >> 16);
}
__device__ __forceinline__ float bf2f(unsigned short h) {
  union { uint32_t u; float f; } v; v.u = ((uint32_t)h) << 16;
  return v.f;
}

// ---------- merged: x fp32 [c][n] -> featB bf16 [n][c]  AND  W -> Wb ----------
// blocks [0,8192): xpose (identical to round-15 k_xpose); [8192,9280): wconv.
__global__ __launch_bounds__(256, 8) void k_prep(const float* __restrict__ x,
                                                 unsigned short* __restrict__ featB,
                                                 const float* __restrict__ W,
                                                 unsigned short* __restrict__ Wb) {
  __shared__ unsigned short sm[64][70];
  int g = blockIdx.x;
  int t = threadIdx.x;
  if (g >= 8192) {                      // ---- W conversion tail
    int idx = (g - 8192) * 256 + t;
    if (idx < HID * KPAD) {
      int o = idx / KPAD;
      int k = idx - o * KPAD;
      float v = (k < KIN) ? W[o * KIN + k] : 0.f;
      Wb[idx] = f2bf(v);
    }
    return;
  }
  int b = g >> 9, cg = (g >> 6) & 7, pt = g & 63;
  int c0 = cg * 64, p0 = pt * 64;
  int lane = t & 63, w = t >> 6;
  const float* xb = x + ((size_t)b * C_IN + c0) * HW + p0;
#pragma unroll
  for (int i = 0; i < 8; ++i) {
    int ch = w * 16 + i * 2;
    float a = xb[(size_t)ch * HW + lane];
    float bq = xb[(size_t)(ch + 1) * HW + lane];
    uint32_t pk = (uint32_t)f2bf(a) | ((uint32_t)f2bf(bq) << 16);
    *(uint32_t*)&sm[lane][ch] = pk;   // ch even, 4B-aligned
  }
  __syncthreads();
#pragma unroll
  for (int i = 0; i < 2; ++i) {
    int px = (t >> 3) + i * 32, kg = t & 7;
    int n = b * 4096 + p0 + px;
    *(bf16x8*)(featB + (size_t)n * KPAD + c0 + kg * 8) = *(const bf16x8*)&sm[px][kg * 8];
  }
}

// ---------- MFMA correlation: band-harvest + dj'-innermost part (round 15) ----------
#define PADC 72
__device__ __forceinline__ int xelem(int sr, int sc, int kg) {
  return (sr * 20 + sc) * PADC + kg * 8;
}

__global__ __launch_bounds__(256, 8) void k_corr(const unsigned short* __restrict__ featB,
                                                 unsigned short* __restrict__ part) {
  __shared__ unsigned short xt[8 * 20 * PADC];  // 23,040 B
  int g = blockIdx.x;
  int bid = (g & 7) * 1024 + (g >> 3);  // bijective XCD swizzle (grid = 8*1024)
  int cs = bid & 7;
  int cg = (bid >> 3) & 3;
  int rg = (bid >> 5) & 15;
  int b  = bid >> 9;
  int t = threadIdx.x;
  int lane = t & 63;
  int w = t >> 6;
  int r0 = rg * 4, c0 = cg * 16;

  // ---- stage: 1280 = 5*256 (px,kg) items from featB; 8 lanes = one px's 128B
  bf16x8 v[5];
  int la[5];
#pragma unroll
  for (int i = 0; i < 5; ++i) {
    int flat = t + i * 256;
    int kg = flat & 7, pxi = flat >> 3;
    int sc = pxi % 20, sr = pxi / 20;
    int ir = r0 - 2 + sr, ic = c0 - 2 + sc;
    la[i] = xelem(sr, sc, kg);
    if ((unsigned)ir < 64u && (unsigned)ic < 64u) {
      int n = b * 4096 + ir * 64 + ic;
      v[i] = *(const bf16x8*)(featB + (size_t)n * KPAD + cs * 64 + kg * 8);
    } else {
      v[i] = (bf16x8){0, 0, 0, 0, 0, 0, 0, 0};
    }
  }
#pragma unroll
  for (int i = 0; i < 5; ++i)
    *(bf16x8*)&xt[la[i]] = v[i];
  __syncthreads();

  int i15 = lane & 15;
  int tq = lane >> 4;

  bf16x8 afr[2];                        // A-frags: centers, reused for all 25
#pragma unroll
  for (int ks = 0; ks < 2; ++ks)
    afr[ks] = *(const bf16x8*)&xt[xelem(w + 2, 2 + i15, ks * 4 + tq)];

  // band geometry (di-independent): reg q of beta-tile bi holds pixel r=4tq+q
  // at dj' = 4bi + i15 - r; served half: bi=0 -> r<=7, bi=1 -> r>=8.
  int nb = b * 4096 + (r0 + w) * 64 + c0;
  bool take[2][4];
#pragma unroll
  for (int bi = 0; bi < 2; ++bi)
#pragma unroll
    for (int qq = 0; qq < 4; ++qq) {
      int r = 4 * tq + qq;
      int djp = bi * 4 + i15 - r;
      take[bi][qq] = (djp >= 0) && (djp <= 4) && (bi == 0 ? (r <= 7) : (r >= 8));
    }

#pragma unroll 1
  for (int di = 0; di < 5; ++di) {
    int sr = w + di;
    unsigned short* pb2 = part + (size_t)(cs * 5 + di) * NPIX * 5 + (size_t)5 * nb;
#pragma unroll
    for (int bi = 0; bi < 2; ++bi) {
      f32x4 acc = (f32x4){0.f, 0.f, 0.f, 0.f};
#pragma unroll
      for (int ks = 0; ks < 2; ++ks) {
        bf16x8 bfr = *(const bf16x8*)&xt[xelem(sr, bi * 4 + i15, ks * 4 + tq)];
        acc = __builtin_amdgcn_mfma_f32_16x16x32_bf16(afr[ks], bfr, acc, 0, 0, 0);
      }
#pragma unroll
      for (int qq = 0; qq < 4; ++qq)
        if (take[bi][qq])
          pb2[4 * bi + 4 * qq + lane] = f2bf(acc[qq]);   // contiguous across lanes
    }
  }
}

// ---------- reduce partials, L2-normalize (4-lane split per pixel) ----------
// Round-17 change vs round 15 (isolated): 4 lanes per pixel (2 cs-slices each,
// 50 scalar loads vs 200) -> 262144 threads = 16 waves/CU (was 4, the latency
// bind); butterfly shfl_xor(1,2) combines; lane csh writes its own 16B quarter
// of featB[n][512..543] -> 64B fully-coalesced per 4 lanes. Traffic unchanged.
__global__ __launch_bounds__(256) void k_norm(const unsigned short* __restrict__ part,
                                              unsigned short* __restrict__ featB) {
  int t = blockIdx.x * 256 + threadIdx.x;   // 1024 blocks x 256
  int n = t >> 2, csh = t & 3;
  float g[25];
#pragma unroll
  for (int k = 0; k < 25; ++k) g[k] = 0.f;
#pragma unroll
  for (int cc = 0; cc < 2; ++cc) {
    int cs = csh * 2 + cc;
#pragma unroll
    for (int di = 0; di < 5; ++di) {
      const unsigned short* pp = part + ((size_t)(cs * 5 + di) * NPIX + n) * 5;
#pragma unroll
      for (int dj = 0; dj < 5; ++dj)
        g[di * 5 + dj] += bf2f(pp[dj]);
    }
  }
#pragma unroll
  for (int k = 0; k < 25; ++k) {
    g[k] += __shfl_xor(g[k], 1);
    g[k] += __shfl_xor(g[k], 2);
  }
  float ss = 0.f;
#pragma unroll
  for (int k = 0; k < 25; ++k) ss += g[k] * g[k];
  float inv = 1.0f / sqrtf(ss + 1e-6f);
  unsigned short buf[8];
#pragma unroll
  for (int j = 0; j < 8; ++j) {
    int k = csh * 8 + j;                // csh=3 -> k 24..31 (25..31 zero-pad)
    buf[j] = (k < 25) ? f2bf(g[k] * inv) : 0;
  }
  *(bf16x8*)(featB + (size_t)n * KPAD + 512 + csh * 8) = *(bf16x8*)buf;
}

// ---------- GEMM: out(512 x 65536) = Wb(512 x 544) * featB(65536 x 544)^T ----------
typedef __attribute__((address_space(3))) unsigned int as3_uint;
typedef const __attribute__((address_space(1))) unsigned int as1_uint;

__device__ __forceinline__ void glds16(const void* g, void* l) {
  __builtin_amdgcn_global_load_lds((as1_uint*)g, (as3_uint*)l, 16, 0, 0);
}

__global__ __launch_bounds__(256) void k_gemm(const unsigned short* __restrict__ Wb,
                                              const unsigned short* __restrict__ featB,
                                              const float* __restrict__ bias,
                                              float* __restrict__ out) {
  __shared__ __attribute__((aligned(16))) unsigned short As[2][4096]; // [128 m][32 k], swz
  __shared__ __attribute__((aligned(16))) unsigned short Bs[2][4096]; // [128 n][32 k], swz
  int g = blockIdx.x;
  int bid = (g & 7) * 256 + (g >> 3);
  int mt = bid & 3;
  int nt = bid >> 2;
  int m0 = mt * 128;
  int n0 = nt * 128;
  int tid = threadIdx.x;
  int wave = tid >> 6;
  int lane = tid & 63;
  int wm = wave >> 1;
  int wn = wave & 1;
  int kg = lane >> 4;

  uint32_t aOff[4], bOff[4];
#pragma unroll
  for (int r = 0; r < 4; ++r) {
    int rr = wm * 64 + r * 16 + (lane & 15);
    aOff[r] = rr * 64 + ((kg ^ ((rr >> 1) & 3)) << 4);
  }
#pragma unroll
  for (int cb = 0; cb < 4; ++cb) {
    int rr = wn * 64 + cb * 16 + (lane & 15);
    bOff[cb] = rr * 64 + ((kg ^ ((rr >> 1) & 3)) << 4);
  }

  f32x4 acc[4][4];
#pragma unroll
  for (int r = 0; r < 4; ++r)
#pragma unroll
    for (int cb = 0; cb < 4; ++cb)
      acc[r][cb] = (f32x4){0.f, 0.f, 0.f, 0.f};

  auto STAGE = [&](int buf, int k0) {
#pragma unroll
    for (int qq = 0; qq < 2; ++qq) {
      int ci = wave * 2 + qq;
      int i = ci * 64 + lane;
      int rr = i >> 2;
      int slot = i & 3;
      int k8 = slot ^ ((rr >> 1) & 3);
      glds16(Wb + (size_t)(m0 + rr) * KPAD + k0 + k8 * 8, (char*)&As[buf][0] + ci * 1024);
      glds16(featB + (size_t)(n0 + rr) * KPAD + k0 + k8 * 8, (char*)&Bs[buf][0] + ci * 1024);
    }
  };

  STAGE(0, 0);
  __syncthreads();
  int cur = 0;
#pragma unroll 1
  for (int t = 0; t < 17; ++t) {
    if (t < 16) STAGE(cur ^ 1, (t + 1) * 32);
    const char* Ab = (const char*)&As[cur][0];
    const char* Bb = (const char*)&Bs[cur][0];
    bf16x8 af[4], bf[4];
#pragma unroll
    for (int r = 0; r < 4; ++r)
      af[r] = *(const bf16x8*)(Ab + aOff[r]);
#pragma unroll
    for (int cb = 0; cb < 4; ++cb)
      bf[cb] = *(const bf16x8*)(Bb + bOff[cb]);
#pragma unroll
    for (int cb = 0; cb < 4; ++cb)
#pragma unroll
      for (int r = 0; r < 4; ++r)
        acc[r][cb] = __builtin_amdgcn_mfma_f32_16x16x32_bf16(af[r], bf[cb], acc[r][cb], 0, 0, 0);
    __syncthreads();
    cur ^= 1;
  }

  int bb = n0 >> 12;
  int hwb = n0 & 4095;
  float* outb = out + (size_t)bb * (HID * HW) + hwb;
#pragma unroll
  for (int r = 0; r < 4; ++r) {
    int row0 = m0 + wm * 64 + r * 16 + (lane >> 4) * 4;
    float bv[4];
#pragma unroll
    for (int j = 0; j < 4; ++j) bv[j] = bias[row0 + j];
#pragma unroll
    for (int cb = 0; cb < 4; ++cb) {
      int col = wn * 64 + cb * 16 + (lane & 15);
#pragma unroll
      for (int j = 0; j < 4; ++j) {
        float v2 = acc[r][cb][j] + bv[j];
        v2 = fmaxf(v2, 0.f);
        outb[(size_t)(row0 + j) * HW + col] = v2;
      }
    }
  }
}

extern "C" void kernel_launch(void* const* d_in, const int* in_sizes, int n_in,
                              void* d_out, int out_size, void* d_ws, size_t ws_size,
                              hipStream_t stream) {
  const float* x = (const float*)d_in[0];
  const float* W = (const float*)d_in[1];
  const float* bias = (const float*)d_in[2];
  float* out = (float*)d_out;
  char* ws = (char*)d_ws;
  // ws: featB 65536x544 bf16 = 71,303,168; Wb 512x544 bf16 = 557,056;
  //     part 40 x (65536*5) bf16 = 26,214,400  (total ~98.07 MB)
  unsigned short* featB = (unsigned short*)ws;
  unsigned short* Wb = (unsigned short*)(ws + 71303168);
  unsigned short* part = (unsigned short*)(ws + 71860224);

  k_prep<<<9280, 256, 0, stream>>>(x, featB, W, Wb);
  k_corr<<<8192, 256, 0, stream>>>(featB, part);
  k_norm<<<1024, 256, 0, stream>>>(part, featB);
  k_gemm<<<2048, 256, 0, stream>>>(Wb, featB, bias, out);
}